// Round 7
// baseline (1404.474 us; speedup 1.0000x reference)
//
#include <hip/hip_runtime.h>
#include <cstdint>
#include <cstddef>

#define NN 100000
#define EE 1600000
#define HH 128
#define NB_N 391    // ceil(NN/256)
#define NBKT 391    // buckets of 256 dst nodes
#define CAP 5120    // staging capacity per bucket

// state slots: [0..3] radix-pick, [8] int64-layout flag, [12..14] alive counters, [16..17] edge counters

typedef float floatx2 __attribute__((ext_vector_type(2)));

static __device__ __forceinline__ unsigned fsort_(float f){
  unsigned u = __float_as_uint(f);
  return (u & 0x80000000u) ? ~u : (u | 0x80000000u);
}
static __device__ __forceinline__ unsigned bfbits_(float f){
  unsigned u = __float_as_uint(f);
  return (u + 0x7FFFu + ((u >> 16) & 1u)) >> 16;
}
static __device__ __forceinline__ unsigned bfpack_(float f0, float f1){
  return bfbits_(f0) | (bfbits_(f1) << 16);
}
static __device__ __forceinline__ float bflo_(unsigned u){ return __uint_as_float(u << 16); }
static __device__ __forceinline__ float bfhi_(unsigned u){ return __uint_as_float(u & 0xFFFF0000u); }

// ---------- probe edge dtype + zero counters ----------
__global__ void k_edgeflag(const int* __restrict__ ei, unsigned* __restrict__ state,
                           unsigned* __restrict__ bktcnt){
  int t = threadIdx.x; // 256
  if(t < 64){
    int v = ei[2*t + 1];
    unsigned long long m = __ballot(v != 0);
    if(t == 0) state[8] = (m == 0ull) ? 1u : 0u;
  }
  if(t >= 12 && t < 24) state[t] = 0u;
  for(int j=t; j<NBKT; j+=256) bktcnt[j] = 0u;
}

// ---------- pass A: bin edges into per-bucket staging ----------
__global__ __launch_bounds__(256) void k_binA(const int* __restrict__ ei,
                     const unsigned* __restrict__ state,
                     unsigned* __restrict__ bktcnt, unsigned* __restrict__ staging){
  __shared__ unsigned lcnt[NBKT];
  __shared__ unsigned lloc[NBKT];
  int t = threadIdx.x;
  for(int j=t; j<NBKT; j+=256){ lcnt[j] = 0u; lloc[j] = 0u; }
  bool i64 = (state[8] != 0u);
  int e0 = blockIdx.x*4096;
  int es[16], ed[16];
  #pragma unroll
  for(int k=0;k<16;k++){
    int e = e0 + k*256 + t;
    int s = -1, d = 0;
    if(e < EE){
      if(i64){ s = ei[2*e]; d = ei[2*EE + 2*e]; }
      else   { s = ei[e];   d = ei[EE + e]; }
    }
    es[k] = s; ed[k] = d;
  }
  __syncthreads();
  #pragma unroll
  for(int k=0;k<16;k++){
    if(es[k] >= 0) atomicAdd(&lcnt[ed[k]>>8], 1u);
  }
  __syncthreads();
  for(int j=t; j<NBKT; j+=256){
    unsigned c = lcnt[j];
    lcnt[j] = c ? atomicAdd(&bktcnt[j], c) : 0u;
  }
  __syncthreads();
  #pragma unroll
  for(int k=0;k<16;k++){
    if(es[k] >= 0){
      int b = ed[k] >> 8;
      unsigned off = lcnt[b] + atomicAdd(&lloc[b], 1u);
      if(off < CAP)
        staging[(unsigned)b*CAP + off] = (unsigned)es[k] | (((unsigned)(ed[k] & 255)) << 17);
    }
  }
}

// ---------- pass B: per-bucket CSR (computes own bucket base; no scan kernel) ----------
__global__ __launch_bounds__(256) void k_binB(const unsigned* __restrict__ staging,
                     const unsigned* __restrict__ bktcnt,
                     int* __restrict__ rs, int* __restrict__ rl, int* __restrict__ col,
                     float* __restrict__ dinv){
  __shared__ unsigned hist[256];
  __shared__ unsigned pref[256];
  __shared__ unsigned lfill[256];
  __shared__ unsigned baseSh;
  int t = threadIdx.x;
  int b = blockIdx.x;
  // base = sum bktcnt[0..b)
  unsigned s = 0;
  for(int j=t; j<b; j+=256) s += bktcnt[j];
  pref[t] = s;
  __syncthreads();
  for(int off=128; off>0; off>>=1){
    if(t < off) pref[t] += pref[t+off];
    __syncthreads();
  }
  if(t == 0) baseSh = pref[0];
  __syncthreads();
  unsigned base = baseSh;
  unsigned cnt = bktcnt[b]; if(cnt > CAP) cnt = CAP;
  hist[t] = 0u; lfill[t] = 0u;
  __syncthreads();
  const unsigned* st = staging + (unsigned)b*CAP;
  for(unsigned i=t; i<cnt; i+=256) atomicAdd(&hist[st[i]>>17], 1u);
  __syncthreads();
  unsigned h = hist[t];
  pref[t] = h;
  __syncthreads();
  for(int off=1; off<256; off<<=1){
    unsigned u = (t >= off) ? pref[t-off] : 0u;
    __syncthreads();
    pref[t] += u;
    __syncthreads();
  }
  unsigned excl = pref[t] - h;
  int node = b*256 + t;
  if(node < NN){
    rs[node] = (int)(base + excl);
    rl[node] = (int)h;
    dinv[node] = rsqrtf(1.f + (float)h);   // layer-1: all alive
  }
  __syncthreads();
  pref[t] = excl;
  __syncthreads();
  for(unsigned i=t; i<cnt; i+=256){
    unsigned w = st[i];
    unsigned dl = w >> 17;
    unsigned pos = base + pref[dl] + atomicAdd(&lfill[dl], 1u);
    col[pos] = (int)(w & 0x1FFFFu);
  }
}

// ---------- GEMM: y8 = fp8((gate .* x) @ W) ----------
template<int MODE>  // 0: fp32 input, identity rows; 1: bf16 input, alist rows, gated
__global__ __launch_bounds__(256) void k_gemm(const void* __restrict__ xin_,
        const float* __restrict__ gate, const int* __restrict__ alist, int nrows,
        const float* __restrict__ W, unsigned char* __restrict__ y8){
  __shared__ float sX[16][68];
  __shared__ float sW[16][64];
  __shared__ int rowid[64];
  __shared__ float rowg[64];
  int row0 = blockIdx.x*64, col0 = blockIdx.y*64;
  int t = threadIdx.x;
  if(t < 64){
    int gr = row0 + t;
    int node = -1; float gg = 0.f;
    if(gr < nrows){
      node = MODE ? alist[gr] : gr;
      gg = MODE ? gate[node] : 1.f;
    }
    rowid[t] = node; rowg[t] = gg;
  }
  __syncthreads();
  int tx = t & 15, ty = t >> 4;
  float acc[4][4] = {{0.f}};
  const float* xf = (const float*)xin_;
  const unsigned short* xh = (const unsigned short*)xin_;
  for(int kb=0; kb<HH; kb+=16){
    #pragma unroll
    for(int j=0;j<4;j++){
      int r = (t>>4) + j*16;
      int k = t & 15;
      int node = rowid[r];
      float v = 0.f;
      if(node >= 0){
        if(MODE) v = __uint_as_float(((unsigned)xh[(size_t)node*HH + kb + k]) << 16) * rowg[r];
        else     v = xf[(size_t)node*HH + kb + k];
      }
      sX[k][r] = v;
    }
    #pragma unroll
    for(int j=0;j<4;j++){
      int k = (t>>6) + j*4;
      int c = t & 63;
      sW[k][c] = W[(size_t)(kb+k)*HH + col0 + c];
    }
    __syncthreads();
    #pragma unroll
    for(int k=0;k<16;k++){
      float4 xv = *(const float4*)&sX[k][ty*4];
      float4 wv = *(const float4*)&sW[k][tx*4];
      float xs[4] = {xv.x, xv.y, xv.z, xv.w};
      float wsv[4] = {wv.x, wv.y, wv.z, wv.w};
      #pragma unroll
      for(int a=0;a<4;a++)
        #pragma unroll
        for(int b=0;b<4;b++)
          acc[a][b] += xs[a]*wsv[b];
    }
    __syncthreads();
  }
  #pragma unroll
  for(int a=0;a<4;a++){
    int node = rowid[ty*4 + a];
    if(node >= 0){
      int u = __builtin_amdgcn_cvt_pk_fp8_f32(acc[a][0], acc[a][1], 0, false);
      u = __builtin_amdgcn_cvt_pk_fp8_f32(acc[a][2], acc[a][3], u, true);
      *(unsigned*)&y8[(size_t)node*HH + col0 + tx*4] = (unsigned)u;
    }
  }
}

// ---------- aggregate: one wave per node, 4 edge-groups x 16 col-lanes, fp8 gather ----------
template<int LIST>
__global__ __launch_bounds__(256) void k_agg(const unsigned char* __restrict__ y8,
        const float* __restrict__ dinv,
        const int* __restrict__ rs, const int* __restrict__ rl,
        const int* __restrict__ col, const int* __restrict__ alist,
        const float* __restrict__ bias, const float* __restrict__ wsc,
        unsigned short* __restrict__ h16, float* __restrict__ p,
        unsigned* __restrict__ hist){
  if(blockIdx.x < 512) hist[blockIdx.x*256 + threadIdx.x] = 0u;
  int w = (blockIdx.x*256 + threadIdx.x) >> 6;
  int lane = threadIdx.x & 63;
  int g = lane >> 4, c = lane & 15;
  int node = LIST ? alist[w] : w;
  float di = dinv[node];
  int e0 = rs[node], len = rl[node];
  float a0=0,a1=0,a2=0,a3=0,a4=0,a5=0,a6=0,a7=0;
  int i = g;
  for(; i + 4 < len; i += 8){
    int s0 = col[e0+i], s1 = col[e0+i+4];
    float d0 = dinv[s0], d1 = dinv[s1];
    uint2 v0 = ((const uint2*)(y8 + (size_t)s0*HH))[c];
    uint2 v1 = ((const uint2*)(y8 + (size_t)s1*HH))[c];
    floatx2 p0a = __builtin_amdgcn_cvt_pk_f32_fp8((int)v0.x, false);
    floatx2 p0b = __builtin_amdgcn_cvt_pk_f32_fp8((int)v0.x, true);
    floatx2 p0c = __builtin_amdgcn_cvt_pk_f32_fp8((int)v0.y, false);
    floatx2 p0d = __builtin_amdgcn_cvt_pk_f32_fp8((int)v0.y, true);
    floatx2 p1a = __builtin_amdgcn_cvt_pk_f32_fp8((int)v1.x, false);
    floatx2 p1b = __builtin_amdgcn_cvt_pk_f32_fp8((int)v1.x, true);
    floatx2 p1c = __builtin_amdgcn_cvt_pk_f32_fp8((int)v1.y, false);
    floatx2 p1d = __builtin_amdgcn_cvt_pk_f32_fp8((int)v1.y, true);
    a0 += d0*p0a.x + d1*p1a.x;  a1 += d0*p0a.y + d1*p1a.y;
    a2 += d0*p0b.x + d1*p1b.x;  a3 += d0*p0b.y + d1*p1b.y;
    a4 += d0*p0c.x + d1*p1c.x;  a5 += d0*p0c.y + d1*p1c.y;
    a6 += d0*p0d.x + d1*p1d.x;  a7 += d0*p0d.y + d1*p1d.y;
  }
  if(i < len){
    int s = col[e0+i];
    float ds = dinv[s];
    uint2 v = ((const uint2*)(y8 + (size_t)s*HH))[c];
    floatx2 pa = __builtin_amdgcn_cvt_pk_f32_fp8((int)v.x, false);
    floatx2 pb = __builtin_amdgcn_cvt_pk_f32_fp8((int)v.x, true);
    floatx2 pc = __builtin_amdgcn_cvt_pk_f32_fp8((int)v.y, false);
    floatx2 pd = __builtin_amdgcn_cvt_pk_f32_fp8((int)v.y, true);
    a0 += ds*pa.x; a1 += ds*pa.y;
    a2 += ds*pb.x; a3 += ds*pb.y;
    a4 += ds*pc.x; a5 += ds*pc.y;
    a6 += ds*pd.x; a7 += ds*pd.y;
  }
  a0 += __shfl_xor(a0,16,64); a0 += __shfl_xor(a0,32,64);
  a1 += __shfl_xor(a1,16,64); a1 += __shfl_xor(a1,32,64);
  a2 += __shfl_xor(a2,16,64); a2 += __shfl_xor(a2,32,64);
  a3 += __shfl_xor(a3,16,64); a3 += __shfl_xor(a3,32,64);
  a4 += __shfl_xor(a4,16,64); a4 += __shfl_xor(a4,32,64);
  a5 += __shfl_xor(a5,16,64); a5 += __shfl_xor(a5,32,64);
  a6 += __shfl_xor(a6,16,64); a6 += __shfl_xor(a6,32,64);
  a7 += __shfl_xor(a7,16,64); a7 += __shfl_xor(a7,32,64);
  uint2 sv = ((const uint2*)(y8 + (size_t)node*HH))[c];
  floatx2 sa = __builtin_amdgcn_cvt_pk_f32_fp8((int)sv.x, false);
  floatx2 sb = __builtin_amdgcn_cvt_pk_f32_fp8((int)sv.x, true);
  floatx2 sc = __builtin_amdgcn_cvt_pk_f32_fp8((int)sv.y, false);
  floatx2 sd = __builtin_amdgcn_cvt_pk_f32_fp8((int)sv.y, true);
  const float4* b4 = (const float4*)bias;
  float4 bb0 = b4[2*c], bb1 = b4[2*c+1];
  float d2 = di*di;
  float o0 = fmaxf(di*a0 + d2*sa.x + bb0.x, 0.f);
  float o1 = fmaxf(di*a1 + d2*sa.y + bb0.y, 0.f);
  float o2 = fmaxf(di*a2 + d2*sb.x + bb0.z, 0.f);
  float o3 = fmaxf(di*a3 + d2*sb.y + bb0.w, 0.f);
  float o4 = fmaxf(di*a4 + d2*sc.x + bb1.x, 0.f);
  float o5 = fmaxf(di*a5 + d2*sc.y + bb1.y, 0.f);
  float o6 = fmaxf(di*a6 + d2*sd.x + bb1.z, 0.f);
  float o7 = fmaxf(di*a7 + d2*sd.y + bb1.w, 0.f);
  if(g == 0){
    uint4 o;
    o.x = bfpack_(o0,o1); o.y = bfpack_(o2,o3);
    o.z = bfpack_(o4,o5); o.w = bfpack_(o6,o7);
    ((uint4*)(h16 + (size_t)node*HH))[c] = o;
  }
  const float4* w4 = (const float4*)wsc;
  float4 w0 = w4[2*c], w1 = w4[2*c+1];
  float pp = o0*w0.x + o1*w0.y + o2*w0.z + o3*w0.w
           + o4*w1.x + o5*w1.y + o6*w1.z + o7*w1.w;
  pp += __shfl_xor(pp, 1, 64);
  pp += __shfl_xor(pp, 2, 64);
  pp += __shfl_xor(pp, 4, 64);
  pp += __shfl_xor(pp, 8, 64);
  if(lane == 0) p[node] = pp;
}

// ---------- score + fused hi-histogram ----------
template<int LIST>
__global__ void k_score(const float* __restrict__ p, const float* __restrict__ dinv,
                        const int* __restrict__ rs, const int* __restrict__ rl,
                        const int* __restrict__ col, const int* __restrict__ alist, int n,
                        const float* __restrict__ bs, float* __restrict__ score,
                        unsigned* __restrict__ key, unsigned* __restrict__ hist){
  int w = blockIdx.x*256 + threadIdx.x;
  if(w >= n) return;
  int i = LIST ? alist[w] : w;
  float di = dinv[i];
  float s = 0.f;
  int e0 = rs[i], len = rl[i];
  for(int e=e0; e<e0+len; e++){
    int cidx = col[e];
    s += dinv[cidx]*p[cidx];
  }
  float sc = di*s + di*di*p[i] + bs[0];
  score[i] = sc;
  unsigned kv = fsort_(sc);
  key[i] = kv;
  atomicAdd(&hist[kv>>16], 1u);
}

// ---------- radix select ----------
__global__ void k_hist_lo(const unsigned* __restrict__ key, const unsigned* __restrict__ state,
                          unsigned* __restrict__ histB){
  int i = blockIdx.x*256 + threadIdx.x;
  if(i < NN){
    unsigned kv = key[i];
    if((kv >> 16) == state[0]) atomicAdd(&histB[kv & 0xFFFFu], 1u);
  }
}
__global__ void k_pick(const unsigned* __restrict__ hist, unsigned* __restrict__ state,
                       int k_in, int mode){
  __shared__ unsigned csum[256];
  int t = threadIdx.x;
  const uint4* h4 = (const uint4*)(hist + t*256);
  unsigned s = 0;
  for(int j=0;j<64;j++){ uint4 v = h4[j]; s += v.x+v.y+v.z+v.w; }
  csum[t] = s;
  __syncthreads();
  for(int off=1; off<256; off<<=1){
    unsigned v = (t+off < 256) ? csum[t+off] : 0u;
    __syncthreads();
    csum[t] += v;
    __syncthreads();
  }
  unsigned k = (mode == 0) ? (unsigned)k_in : state[1];
  unsigned above = csum[t] - s;
  if(above < k && above + s >= k){
    unsigned run = above;
    for(int j=255; j>=0; j--){
      unsigned c = hist[t*256+j];
      if(run + c >= k){
        if(mode == 0){ state[0] = (unsigned)(t*256+j); state[1] = k - run; }
        else { state[2] = (state[0] << 16) | (unsigned)(t*256+j); state[3] = k - run; }
        break;
      }
      run += c;
    }
  }
}

// ---------- mask + gate + alive-list + fused per-block readout partials ----------
__global__ __launch_bounds__(256) void k_maskCR(unsigned* __restrict__ key,
        const float* __restrict__ score, const unsigned* __restrict__ state,
        const unsigned short* __restrict__ h16,
        unsigned char* __restrict__ selm, float* __restrict__ gate,
        int* __restrict__ alist_out, unsigned* __restrict__ acounter,
        float* __restrict__ rpart, int slotbase){
  __shared__ int wcnt[4];
  __shared__ int priorSh;
  __shared__ int redi[256];
  __shared__ float gl[256];
  __shared__ unsigned char slf[256];
  __shared__ float4 red[256];
  __shared__ float out2[256];
  int t = threadIdx.x;
  int i = blockIdx.x*256 + t;
  unsigned T = state[2];
  int trem = (int)state[3];
  unsigned kv = (i < NN) ? key[i] : 0u;
  bool match = (kv == T);
  unsigned long long m = __ballot(match);
  int lane = t & 63, wid = t >> 6;
  if(lane == 0) wcnt[wid] = __popcll(m);
  if(t == 0) priorSh = 0;
  __syncthreads();
  int hasMatch = wcnt[0] | wcnt[1] | wcnt[2] | wcnt[3];
  int bbase = blockIdx.x*256;
  if(hasMatch){   // rare: only blocks containing threshold-tied keys
    int cm = 0;
    for(int j = t*4; j < bbase; j += 1024){
      uint4 kk = *(const uint4*)&key[j];
      cm += (kk.x==T) + (kk.y==T) + (kk.z==T) + (kk.w==T);
    }
    redi[t] = cm;
    __syncthreads();
    for(int off=128; off>0; off>>=1){
      if(t < off) redi[t] += redi[t+off];
      __syncthreads();
    }
    if(t == 0) priorSh = redi[0];
    __syncthreads();
  }
  int pre = 0;
  for(int w=0; w<wid; w++) pre += wcnt[w];
  int lrank = __popcll(m & ((1ull << lane) - 1ull));
  int rank = priorSh + pre + lrank;
  bool sel = (kv > T) || (match && rank < trem);
  float gg = sel ? tanhf(score[i]) : 0.f;
  gl[t] = gg;
  slf[t] = sel ? 1 : 0;
  if(i < NN){
    selm[i] = sel ? 1 : 0;
    gate[i] = gg;
    if(!sel) key[i] = 0u;     // dead keys must be 0 for next layer's select
  }
  unsigned long long sm = __ballot(sel);
  unsigned abase = 0;
  if(lane == 0) abase = atomicAdd(acounter, (unsigned)__popcll(sm));
  abase = (unsigned)__shfl((int)abase, 0, 64);
  if(sel) alist_out[abase + __popcll(sm & ((1ull << lane) - 1ull))] = i;
  __syncthreads();
  // readout partials over this block's selected nodes: 16 col-lanes x 16 node-slots
  int ch = t & 15;
  int slot = t >> 4;
  float mm[8] = {0,0,0,0,0,0,0,0};
  float MM[8] = {-1e30f,-1e30f,-1e30f,-1e30f,-1e30f,-1e30f,-1e30f,-1e30f};
  for(int itr=0; itr<16; itr++){
    int nl = slot + itr*16;
    int node = bbase + nl;
    if(node < NN && slf[nl]){
      float g = gl[nl];
      uint4 v = ((const uint4*)(h16 + (size_t)node*HH))[ch];
      float x0 = g*bflo_(v.x), x1 = g*bfhi_(v.x);
      float x2 = g*bflo_(v.y), x3 = g*bfhi_(v.y);
      float x4 = g*bflo_(v.z), x5 = g*bfhi_(v.z);
      float x6 = g*bflo_(v.w), x7 = g*bfhi_(v.w);
      mm[0]+=x0; mm[1]+=x1; mm[2]+=x2; mm[3]+=x3;
      mm[4]+=x4; mm[5]+=x5; mm[6]+=x6; mm[7]+=x7;
      MM[0]=fmaxf(MM[0],x0); MM[1]=fmaxf(MM[1],x1); MM[2]=fmaxf(MM[2],x2); MM[3]=fmaxf(MM[3],x3);
      MM[4]=fmaxf(MM[4],x4); MM[5]=fmaxf(MM[5],x5); MM[6]=fmaxf(MM[6],x6); MM[7]=fmaxf(MM[7],x7);
    }
  }
  #pragma unroll
  for(int half=0; half<2; half++){
    red[t] = make_float4(mm[half*4+0],mm[half*4+1],mm[half*4+2],mm[half*4+3]);
    __syncthreads();
    if(t < 16){
      float4 sacc = red[t];
      for(int j=1;j<16;j++){
        float4 o = red[t + 16*j];
        sacc.x += o.x; sacc.y += o.y; sacc.z += o.z; sacc.w += o.w;
      }
      int d = t*8 + half*4;
      out2[d+0] = sacc.x; out2[d+1] = sacc.y; out2[d+2] = sacc.z; out2[d+3] = sacc.w;
    }
    __syncthreads();
    red[t] = make_float4(MM[half*4+0],MM[half*4+1],MM[half*4+2],MM[half*4+3]);
    __syncthreads();
    if(t < 16){
      float4 sacc = red[t];
      for(int j=1;j<16;j++){
        float4 o = red[t + 16*j];
        sacc.x = fmaxf(sacc.x,o.x); sacc.y = fmaxf(sacc.y,o.y);
        sacc.z = fmaxf(sacc.z,o.z); sacc.w = fmaxf(sacc.w,o.w);
      }
      int d = 128 + t*8 + half*4;
      out2[d+0] = sacc.x; out2[d+1] = sacc.y; out2[d+2] = sacc.z; out2[d+3] = sacc.w;
    }
    __syncthreads();
  }
  rpart[(size_t)(slotbase + blockIdx.x)*256 + t] = out2[t];
}

// ---------- parallel edge compaction: 16 lanes/node, 1 global atomic/block ----------
__global__ __launch_bounds__(256) void k_compact(const int* __restrict__ alist, int n,
        const unsigned char* __restrict__ selm,
        const int* __restrict__ rs_old, const int* __restrict__ rl_old,
        const int* __restrict__ col_old,
        int* __restrict__ rs_new, int* __restrict__ rl_new, int* __restrict__ col_new,
        float* __restrict__ dinv, unsigned* __restrict__ ecnt){
  __shared__ unsigned gcnt[16];
  __shared__ unsigned gbase[16];
  __shared__ unsigned blkbase;
  int t = threadIdx.x;
  int g = t >> 4, lane = t & 15;
  int gsh = ((t >> 4) & 3) * 16;   // group's bit offset within the 64-lane ballot
  int idx = blockIdx.x*16 + g;
  int node = -1, e0 = 0, len = 0;
  if(idx < n){ node = alist[idx]; e0 = rs_old[node]; len = rl_old[node]; }
  int cnt = 0;
  for(int i=lane; i<len; i+=16) cnt += selm[col_old[e0+i]];
  cnt += __shfl_xor(cnt,1,64); cnt += __shfl_xor(cnt,2,64);
  cnt += __shfl_xor(cnt,4,64); cnt += __shfl_xor(cnt,8,64);
  if(lane == 0) gcnt[g] = (node >= 0) ? (unsigned)cnt : 0u;
  __syncthreads();
  if(t == 0){
    unsigned s = 0;
    for(int j=0;j<16;j++){ gbase[j] = s; s += gcnt[j]; }
    blkbase = s ? atomicAdd(ecnt, s) : 0u;
  }
  __syncthreads();
  unsigned base = blkbase + gbase[g];
  if(node >= 0 && lane == 0){
    rs_new[node] = (int)base;
    rl_new[node] = cnt;
    dinv[node] = rsqrtf(1.f + (float)cnt);
  }
  int pos = (int)base;
  for(int i0=0; i0<len; i0+=16){
    int i = i0 + lane;
    bool keep = false; int s = 0;
    if(i < len){ s = col_old[e0+i]; keep = (selm[s] != 0); }
    unsigned long long b = __ballot(keep);
    unsigned gb = (unsigned)((b >> gsh) & 0xFFFFull);
    int rank = __popc(gb & ((1u << lane) - 1u));
    if(keep) col_new[pos + rank] = s;
    pos += __popc(gb);
  }
}

// ---------- final reduce of readout partials + MLP head + log_softmax ----------
__global__ void k_mlp(const float* __restrict__ rpart,
                      const float* __restrict__ M1, const float* __restrict__ bm1,
                      const float* __restrict__ M2, const float* __restrict__ bm2,
                      const float* __restrict__ M3, const float* __restrict__ bm3,
                      float* __restrict__ out){
  __shared__ float R[256];
  __shared__ float y1[128];
  __shared__ float y2[64];
  __shared__ float y3[16];
  int t = threadIdx.x;
  const float kinv[3] = {1.f/50000.f, 1.f/25000.f, 1.f/12500.f};
  if(t < 128){
    float acc = 0.f;
    for(int l=0; l<3; l++){
      float s0=0.f,s1=0.f,s2=0.f,s3=0.f;
      int base = l*NB_N;
      int j = 0;
      for(; j+3 < NB_N; j += 4){
        s0 += rpart[(size_t)(base+j  )*256 + t];
        s1 += rpart[(size_t)(base+j+1)*256 + t];
        s2 += rpart[(size_t)(base+j+2)*256 + t];
        s3 += rpart[(size_t)(base+j+3)*256 + t];
      }
      for(; j < NB_N; j++) s0 += rpart[(size_t)(base+j)*256 + t];
      acc += ((s0+s1)+(s2+s3)) * kinv[l];
    }
    R[t] = acc;
  } else {
    float acc = 0.f;
    for(int l=0; l<3; l++){
      float m0=-1e30f,m1=-1e30f,m2=-1e30f,m3=-1e30f;
      int base = l*NB_N;
      int j = 0;
      for(; j+3 < NB_N; j += 4){
        m0 = fmaxf(m0, rpart[(size_t)(base+j  )*256 + t]);
        m1 = fmaxf(m1, rpart[(size_t)(base+j+1)*256 + t]);
        m2 = fmaxf(m2, rpart[(size_t)(base+j+2)*256 + t]);
        m3 = fmaxf(m3, rpart[(size_t)(base+j+3)*256 + t]);
      }
      for(; j < NB_N; j++) m0 = fmaxf(m0, rpart[(size_t)(base+j)*256 + t]);
      acc += fmaxf(fmaxf(m0,m1), fmaxf(m2,m3));
    }
    R[t] = acc;
  }
  __syncthreads();
  if(t < 128){
    float a = bm1[t];
    for(int d=0; d<256; d++) a += R[d]*M1[d*128+t];
    y1[t] = fmaxf(a, 0.f);
  }
  __syncthreads();
  if(t < 64){
    float a = bm2[t];
    for(int d=0; d<128; d++) a += y1[d]*M2[d*64+t];
    y2[t] = fmaxf(a, 0.f);
  }
  __syncthreads();
  if(t < 10){
    float a = bm3[t];
    for(int d=0; d<64; d++) a += y2[d]*M3[d*10+t];
    y3[t] = a;
  }
  __syncthreads();
  if(t == 0){
    float mx = -1e30f;
    for(int o=0;o<10;o++) mx = fmaxf(mx, y3[o]);
    float s = 0.f;
    for(int o=0;o<10;o++) s += expf(y3[o]-mx);
    float ls = logf(s);
    for(int o=0;o<10;o++) out[o] = y3[o] - mx - ls;
  }
}

extern "C" void kernel_launch(void* const* d_in, const int* in_sizes, int n_in,
                              void* d_out, int out_size, void* d_ws, size_t ws_size,
                              hipStream_t stream){
  (void)in_sizes; (void)n_in; (void)out_size; (void)ws_size;
  const float* x  = (const float*)d_in[0];
  const int*   ei = (const int*)d_in[1];
  const float* W[3]   = {(const float*)d_in[2],  (const float*)d_in[6],  (const float*)d_in[10]};
  const float* bb[3]  = {(const float*)d_in[3],  (const float*)d_in[7],  (const float*)d_in[11]};
  const float* wsc[3] = {(const float*)d_in[4],  (const float*)d_in[8],  (const float*)d_in[12]};
  const float* bsc[3] = {(const float*)d_in[5],  (const float*)d_in[9],  (const float*)d_in[13]};
  const float* M1  = (const float*)d_in[14];
  const float* bm1 = (const float*)d_in[15];
  const float* M2  = (const float*)d_in[16];
  const float* bm2 = (const float*)d_in[17];
  const float* M3  = (const float*)d_in[18];
  const float* bm3 = (const float*)d_in[19];
  float* out = (float*)d_out;

  char* base = (char*)d_ws;
  size_t off = 0;
  auto alloc = [&](size_t bytes)->char*{
    char* ptr = base + off;
    off += (bytes + 511) & ~(size_t)511;
    return ptr;
  };
  unsigned char*  y8   = (unsigned char*) alloc((size_t)NN*HH);
  unsigned short* h16  = (unsigned short*)alloc((size_t)NN*HH*2);
  int*      col0      = (int*)     alloc((size_t)EE*4);
  int*      col1      = (int*)     alloc((size_t)EE*4);
  int*      col2      = (int*)     alloc((size_t)EE*4);
  unsigned* staging   = (unsigned*)alloc((size_t)NBKT*CAP*4);
  int*      rs0       = (int*)     alloc((size_t)NN*4);
  int*      rl0       = (int*)     alloc((size_t)NN*4);
  int*      rs1       = (int*)     alloc((size_t)NN*4);
  int*      rl1       = (int*)     alloc((size_t)NN*4);
  int*      rs2       = (int*)     alloc((size_t)NN*4);
  int*      rl2       = (int*)     alloc((size_t)NN*4);
  float*    dinv      = (float*)   alloc((size_t)NN*4);
  float*    pbuf      = (float*)   alloc((size_t)NN*4);
  float*    score     = (float*)   alloc((size_t)NN*4);
  float*    gate      = (float*)   alloc((size_t)NN*4);
  unsigned* key       = (unsigned*)alloc((size_t)NN*4);
  unsigned char* selm = (unsigned char*)alloc((size_t)NN);
  int*      alistA    = (int*)     alloc((size_t)50000*4);
  int*      alistB    = (int*)     alloc((size_t)25000*4);
  unsigned* hist      = (unsigned*)alloc((size_t)2*65536*4);
  unsigned* bktcnt    = (unsigned*)alloc((size_t)(NBKT+1)*4);
  unsigned* state     = (unsigned*)alloc(256);
  float*    rpart     = (float*)   alloc((size_t)3*NB_N*256*4);

  // CSR build
  k_edgeflag<<<1,256,0,stream>>>(ei, state, bktcnt);
  k_binA<<<NBKT,256,0,stream>>>(ei, state, bktcnt, staging);
  k_binB<<<NBKT,256,0,stream>>>(staging, bktcnt, rs0, rl0, col0, dinv);

  // ---- layer 1 (identity rows: all 100000 alive) ----
  k_gemm<0><<<dim3(1563,2),256,0,stream>>>(x, nullptr, nullptr, NN, W[0], y8);
  k_agg<0><<<25000,256,0,stream>>>(y8, dinv, rs0, rl0, col0, nullptr, bb[0], wsc[0], h16, pbuf, hist);
  k_score<0><<<NB_N,256,0,stream>>>(pbuf, dinv, rs0, rl0, col0, nullptr, NN, bsc[0], score, key, hist);
  k_pick<<<1,256,0,stream>>>(hist, state, 50000, 0);
  k_hist_lo<<<NB_N,256,0,stream>>>(key, state, hist + 65536);
  k_pick<<<1,256,0,stream>>>(hist + 65536, state, 0, 1);
  k_maskCR<<<NB_N,256,0,stream>>>(key, score, state, h16, selm, gate, alistA, state+12, rpart, 0);
  k_compact<<<3125,256,0,stream>>>(alistA, 50000, selm, rs0, rl0, col0, rs1, rl1, col1, dinv, state+16);

  // ---- layer 2 (50000 alive) ----
  k_gemm<1><<<dim3(782,2),256,0,stream>>>(h16, gate, alistA, 50000, W[1], y8);
  k_agg<1><<<12500,256,0,stream>>>(y8, dinv, rs1, rl1, col1, alistA, bb[1], wsc[1], h16, pbuf, hist);
  k_score<1><<<196,256,0,stream>>>(pbuf, dinv, rs1, rl1, col1, alistA, 50000, bsc[1], score, key, hist);
  k_pick<<<1,256,0,stream>>>(hist, state, 25000, 0);
  k_hist_lo<<<NB_N,256,0,stream>>>(key, state, hist + 65536);
  k_pick<<<1,256,0,stream>>>(hist + 65536, state, 0, 1);
  k_maskCR<<<NB_N,256,0,stream>>>(key, score, state, h16, selm, gate, alistB, state+13, rpart, NB_N);
  k_compact<<<1563,256,0,stream>>>(alistB, 25000, selm, rs1, rl1, col1, rs2, rl2, col2, dinv, state+17);

  // ---- layer 3 (25000 alive) ----
  k_gemm<1><<<dim3(391,2),256,0,stream>>>(h16, gate, alistB, 25000, W[2], y8);
  k_agg<1><<<6250,256,0,stream>>>(y8, dinv, rs2, rl2, col2, alistB, bb[2], wsc[2], h16, pbuf, hist);
  k_score<1><<<98,256,0,stream>>>(pbuf, dinv, rs2, rl2, col2, alistB, 25000, bsc[2], score, key, hist);
  k_pick<<<1,256,0,stream>>>(hist, state, 12500, 0);
  k_hist_lo<<<NB_N,256,0,stream>>>(key, state, hist + 65536);
  k_pick<<<1,256,0,stream>>>(hist + 65536, state, 0, 1);
  k_maskCR<<<NB_N,256,0,stream>>>(key, score, state, h16, selm, gate, alistA, state+14, rpart, 2*NB_N);

  k_mlp<<<1,256,0,stream>>>(rpart, M1, bm1, M2, bm2, M3, bm3, out);
}

// Round 8
// 802.915 us; speedup vs baseline: 1.7492x; 1.7492x over previous
//
#include <hip/hip_runtime.h>
#include <cstdint>
#include <cstddef>

#define NN 100000
#define EE 1600000
#define HH 128
#define NB_N 391    // ceil(NN/256)
#define NBKT 391    // buckets of 256 dst nodes
#define CAP 5120    // staging capacity per bucket

// state slots: [0..3] radix-pick, [8] int64-layout flag, [12..14] alive counters, [16..17] edge counters

static __device__ __forceinline__ unsigned fsort_(float f){
  unsigned u = __float_as_uint(f);
  return (u & 0x80000000u) ? ~u : (u | 0x80000000u);
}
static __device__ __forceinline__ unsigned bfbits_(float f){
  unsigned u = __float_as_uint(f);
  return (u + 0x7FFFu + ((u >> 16) & 1u)) >> 16;
}
static __device__ __forceinline__ unsigned bfpack_(float f0, float f1){
  return bfbits_(f0) | (bfbits_(f1) << 16);
}
static __device__ __forceinline__ float bflo_(unsigned u){ return __uint_as_float(u << 16); }
static __device__ __forceinline__ float bfhi_(unsigned u){ return __uint_as_float(u & 0xFFFF0000u); }

// ---------- probe edge dtype + zero counters ----------
__global__ void k_edgeflag(const int* __restrict__ ei, unsigned* __restrict__ state,
                           unsigned* __restrict__ bktcnt){
  int t = threadIdx.x; // 256
  if(t < 64){
    int v = ei[2*t + 1];
    unsigned long long m = __ballot(v != 0);
    if(t == 0) state[8] = (m == 0ull) ? 1u : 0u;
  }
  if(t >= 12 && t < 24) state[t] = 0u;
  for(int j=t; j<NBKT; j+=256) bktcnt[j] = 0u;
}

// ---------- pass A: bin edges into per-bucket staging ----------
__global__ __launch_bounds__(256) void k_binA(const int* __restrict__ ei,
                     const unsigned* __restrict__ state,
                     unsigned* __restrict__ bktcnt, unsigned* __restrict__ staging){
  __shared__ unsigned lcnt[NBKT];
  __shared__ unsigned lloc[NBKT];
  int t = threadIdx.x;
  for(int j=t; j<NBKT; j+=256){ lcnt[j] = 0u; lloc[j] = 0u; }
  bool i64 = (state[8] != 0u);
  int e0 = blockIdx.x*4096;
  int es[16], ed[16];
  #pragma unroll
  for(int k=0;k<16;k++){
    int e = e0 + k*256 + t;
    int s = -1, d = 0;
    if(e < EE){
      if(i64){ s = ei[2*e]; d = ei[2*EE + 2*e]; }
      else   { s = ei[e];   d = ei[EE + e]; }
    }
    es[k] = s; ed[k] = d;
  }
  __syncthreads();
  #pragma unroll
  for(int k=0;k<16;k++){
    if(es[k] >= 0) atomicAdd(&lcnt[ed[k]>>8], 1u);
  }
  __syncthreads();
  for(int j=t; j<NBKT; j+=256){
    unsigned c = lcnt[j];
    lcnt[j] = c ? atomicAdd(&bktcnt[j], c) : 0u;
  }
  __syncthreads();
  #pragma unroll
  for(int k=0;k<16;k++){
    if(es[k] >= 0){
      int b = ed[k] >> 8;
      unsigned off = lcnt[b] + atomicAdd(&lloc[b], 1u);
      if(off < CAP)
        staging[(unsigned)b*CAP + off] = (unsigned)es[k] | (((unsigned)(ed[k] & 255)) << 17);
    }
  }
}

// ---------- pass B: per-bucket CSR (computes own bucket base; no scan kernel) ----------
__global__ __launch_bounds__(256) void k_binB(const unsigned* __restrict__ staging,
                     const unsigned* __restrict__ bktcnt,
                     int* __restrict__ rs, int* __restrict__ rl, int* __restrict__ col,
                     float* __restrict__ dinv){
  __shared__ unsigned hist[256];
  __shared__ unsigned pref[256];
  __shared__ unsigned lfill[256];
  __shared__ unsigned baseSh;
  int t = threadIdx.x;
  int b = blockIdx.x;
  // base = sum bktcnt[0..b)
  unsigned s = 0;
  for(int j=t; j<b; j+=256) s += bktcnt[j];
  pref[t] = s;
  __syncthreads();
  for(int off=128; off>0; off>>=1){
    if(t < off) pref[t] += pref[t+off];
    __syncthreads();
  }
  if(t == 0) baseSh = pref[0];
  __syncthreads();
  unsigned base = baseSh;
  unsigned cnt = bktcnt[b]; if(cnt > CAP) cnt = CAP;
  hist[t] = 0u; lfill[t] = 0u;
  __syncthreads();
  const unsigned* st = staging + (unsigned)b*CAP;
  for(unsigned i=t; i<cnt; i+=256) atomicAdd(&hist[st[i]>>17], 1u);
  __syncthreads();
  unsigned h = hist[t];
  pref[t] = h;
  __syncthreads();
  for(int off=1; off<256; off<<=1){
    unsigned u = (t >= off) ? pref[t-off] : 0u;
    __syncthreads();
    pref[t] += u;
    __syncthreads();
  }
  unsigned excl = pref[t] - h;
  int node = b*256 + t;
  if(node < NN){
    rs[node] = (int)(base + excl);
    rl[node] = (int)h;
    dinv[node] = rsqrtf(1.f + (float)h);   // layer-1: all alive
  }
  __syncthreads();
  pref[t] = excl;
  __syncthreads();
  for(unsigned i=t; i<cnt; i+=256){
    unsigned w = st[i];
    unsigned dl = w >> 17;
    unsigned pos = base + pref[dl] + atomicAdd(&lfill[dl], 1u);
    col[pos] = (int)(w & 0x1FFFFu);
  }
}

// ---------- GEMM: y16 = bf16((gate .* x) @ W) ----------
template<int MODE>  // 0: fp32 input, identity rows; 1: bf16 input, alist rows, gated
__global__ __launch_bounds__(256) void k_gemm(const void* __restrict__ xin_,
        const float* __restrict__ gate, const int* __restrict__ alist, int nrows,
        const float* __restrict__ W, unsigned short* __restrict__ y16){
  __shared__ float sX[16][68];
  __shared__ float sW[16][64];
  __shared__ int rowid[64];
  __shared__ float rowg[64];
  int row0 = blockIdx.x*64, col0 = blockIdx.y*64;
  int t = threadIdx.x;
  if(t < 64){
    int gr = row0 + t;
    int node = -1; float gg = 0.f;
    if(gr < nrows){
      node = MODE ? alist[gr] : gr;
      gg = MODE ? gate[node] : 1.f;
    }
    rowid[t] = node; rowg[t] = gg;
  }
  __syncthreads();
  int tx = t & 15, ty = t >> 4;
  float acc[4][4] = {{0.f}};
  const float* xf = (const float*)xin_;
  const unsigned short* xh = (const unsigned short*)xin_;
  for(int kb=0; kb<HH; kb+=16){
    #pragma unroll
    for(int j=0;j<4;j++){
      int r = (t>>4) + j*16;
      int k = t & 15;
      int node = rowid[r];
      float v = 0.f;
      if(node >= 0){
        if(MODE) v = __uint_as_float(((unsigned)xh[(size_t)node*HH + kb + k]) << 16) * rowg[r];
        else     v = xf[(size_t)node*HH + kb + k];
      }
      sX[k][r] = v;
    }
    #pragma unroll
    for(int j=0;j<4;j++){
      int k = (t>>6) + j*4;
      int c = t & 63;
      sW[k][c] = W[(size_t)(kb+k)*HH + col0 + c];
    }
    __syncthreads();
    #pragma unroll
    for(int k=0;k<16;k++){
      float4 xv = *(const float4*)&sX[k][ty*4];
      float4 wv = *(const float4*)&sW[k][tx*4];
      float xs[4] = {xv.x, xv.y, xv.z, xv.w};
      float wsv[4] = {wv.x, wv.y, wv.z, wv.w};
      #pragma unroll
      for(int a=0;a<4;a++)
        #pragma unroll
        for(int b=0;b<4;b++)
          acc[a][b] += xs[a]*wsv[b];
    }
    __syncthreads();
  }
  #pragma unroll
  for(int a=0;a<4;a++){
    int node = rowid[ty*4 + a];
    if(node >= 0){
      uint2 o;
      o.x = bfpack_(acc[a][0], acc[a][1]);
      o.y = bfpack_(acc[a][2], acc[a][3]);
      *(uint2*)&y16[(size_t)node*HH + col0 + tx*4] = o;
    }
  }
}

// ---------- aggregate: one wave per node, 4 edge-groups x 16 col-lanes ----------
template<int LIST>
__global__ __launch_bounds__(256) void k_agg(const unsigned short* __restrict__ y16,
        const float* __restrict__ dinv,
        const int* __restrict__ rs, const int* __restrict__ rl,
        const int* __restrict__ col, const int* __restrict__ alist,
        const float* __restrict__ bias, const float* __restrict__ wsc,
        unsigned short* __restrict__ h16, float* __restrict__ p,
        unsigned* __restrict__ hist){
  if(blockIdx.x < 512) hist[blockIdx.x*256 + threadIdx.x] = 0u;
  int w = (blockIdx.x*256 + threadIdx.x) >> 6;
  int lane = threadIdx.x & 63;
  int g = lane >> 4, c = lane & 15;
  int node = LIST ? alist[w] : w;
  float di = dinv[node];
  int e0 = rs[node], len = rl[node];
  float a0=0,a1=0,a2=0,a3=0,a4=0,a5=0,a6=0,a7=0;
  int i = g;
  for(; i + 4 < len; i += 8){
    int s0 = col[e0+i], s1 = col[e0+i+4];
    float d0 = dinv[s0], d1 = dinv[s1];
    uint4 v0 = ((const uint4*)(y16 + (size_t)s0*HH))[c];
    uint4 v1 = ((const uint4*)(y16 + (size_t)s1*HH))[c];
    a0 += d0*bflo_(v0.x) + d1*bflo_(v1.x);
    a1 += d0*bfhi_(v0.x) + d1*bfhi_(v1.x);
    a2 += d0*bflo_(v0.y) + d1*bflo_(v1.y);
    a3 += d0*bfhi_(v0.y) + d1*bfhi_(v1.y);
    a4 += d0*bflo_(v0.z) + d1*bflo_(v1.z);
    a5 += d0*bfhi_(v0.z) + d1*bfhi_(v1.z);
    a6 += d0*bflo_(v0.w) + d1*bflo_(v1.w);
    a7 += d0*bfhi_(v0.w) + d1*bfhi_(v1.w);
  }
  if(i < len){
    int s = col[e0+i];
    float ds = dinv[s];
    uint4 v = ((const uint4*)(y16 + (size_t)s*HH))[c];
    a0 += ds*bflo_(v.x); a1 += ds*bfhi_(v.x);
    a2 += ds*bflo_(v.y); a3 += ds*bfhi_(v.y);
    a4 += ds*bflo_(v.z); a5 += ds*bfhi_(v.z);
    a6 += ds*bflo_(v.w); a7 += ds*bfhi_(v.w);
  }
  a0 += __shfl_xor(a0,16,64); a0 += __shfl_xor(a0,32,64);
  a1 += __shfl_xor(a1,16,64); a1 += __shfl_xor(a1,32,64);
  a2 += __shfl_xor(a2,16,64); a2 += __shfl_xor(a2,32,64);
  a3 += __shfl_xor(a3,16,64); a3 += __shfl_xor(a3,32,64);
  a4 += __shfl_xor(a4,16,64); a4 += __shfl_xor(a4,32,64);
  a5 += __shfl_xor(a5,16,64); a5 += __shfl_xor(a5,32,64);
  a6 += __shfl_xor(a6,16,64); a6 += __shfl_xor(a6,32,64);
  a7 += __shfl_xor(a7,16,64); a7 += __shfl_xor(a7,32,64);
  uint4 sv = ((const uint4*)(y16 + (size_t)node*HH))[c];
  const float4* b4 = (const float4*)bias;
  float4 bb0 = b4[2*c], bb1 = b4[2*c+1];
  float d2 = di*di;
  float o0 = fmaxf(di*a0 + d2*bflo_(sv.x) + bb0.x, 0.f);
  float o1 = fmaxf(di*a1 + d2*bfhi_(sv.x) + bb0.y, 0.f);
  float o2 = fmaxf(di*a2 + d2*bflo_(sv.y) + bb0.z, 0.f);
  float o3 = fmaxf(di*a3 + d2*bfhi_(sv.y) + bb0.w, 0.f);
  float o4 = fmaxf(di*a4 + d2*bflo_(sv.z) + bb1.x, 0.f);
  float o5 = fmaxf(di*a5 + d2*bfhi_(sv.z) + bb1.y, 0.f);
  float o6 = fmaxf(di*a6 + d2*bflo_(sv.w) + bb1.z, 0.f);
  float o7 = fmaxf(di*a7 + d2*bfhi_(sv.w) + bb1.w, 0.f);
  if(g == 0){
    uint4 o;
    o.x = bfpack_(o0,o1); o.y = bfpack_(o2,o3);
    o.z = bfpack_(o4,o5); o.w = bfpack_(o6,o7);
    ((uint4*)(h16 + (size_t)node*HH))[c] = o;
  }
  const float4* w4 = (const float4*)wsc;
  float4 w0 = w4[2*c], w1 = w4[2*c+1];
  float pp = o0*w0.x + o1*w0.y + o2*w0.z + o3*w0.w
           + o4*w1.x + o5*w1.y + o6*w1.z + o7*w1.w;
  pp += __shfl_xor(pp, 1, 64);
  pp += __shfl_xor(pp, 2, 64);
  pp += __shfl_xor(pp, 4, 64);
  pp += __shfl_xor(pp, 8, 64);
  if(lane == 0) p[node] = pp;
}

// ---------- score + fused hi-histogram ----------
template<int LIST>
__global__ void k_score(const float* __restrict__ p, const float* __restrict__ dinv,
                        const int* __restrict__ rs, const int* __restrict__ rl,
                        const int* __restrict__ col, const int* __restrict__ alist, int n,
                        const float* __restrict__ bs, float* __restrict__ score,
                        unsigned* __restrict__ key, unsigned* __restrict__ hist){
  int w = blockIdx.x*256 + threadIdx.x;
  if(w >= n) return;
  int i = LIST ? alist[w] : w;
  float di = dinv[i];
  float s = 0.f;
  int e0 = rs[i], len = rl[i];
  for(int e=e0; e<e0+len; e++){
    int cidx = col[e];
    s += dinv[cidx]*p[cidx];
  }
  float sc = di*s + di*di*p[i] + bs[0];
  score[i] = sc;
  unsigned kv = fsort_(sc);
  key[i] = kv;
  atomicAdd(&hist[kv>>16], 1u);
}

// ---------- radix select ----------
__global__ void k_hist_lo(const unsigned* __restrict__ key, const unsigned* __restrict__ state,
                          unsigned* __restrict__ histB){
  int i = blockIdx.x*256 + threadIdx.x;
  if(i < NN){
    unsigned kv = key[i];
    if((kv >> 16) == state[0]) atomicAdd(&histB[kv & 0xFFFFu], 1u);
  }
}
__global__ void k_pick(const unsigned* __restrict__ hist, unsigned* __restrict__ state,
                       int k_in, int mode){
  __shared__ unsigned csum[256];
  int t = threadIdx.x;
  const uint4* h4 = (const uint4*)(hist + t*256);
  unsigned s = 0;
  for(int j=0;j<64;j++){ uint4 v = h4[j]; s += v.x+v.y+v.z+v.w; }
  csum[t] = s;
  __syncthreads();
  for(int off=1; off<256; off<<=1){
    unsigned v = (t+off < 256) ? csum[t+off] : 0u;
    __syncthreads();
    csum[t] += v;
    __syncthreads();
  }
  unsigned k = (mode == 0) ? (unsigned)k_in : state[1];
  unsigned above = csum[t] - s;
  if(above < k && above + s >= k){
    unsigned run = above;
    for(int j=255; j>=0; j--){
      unsigned c = hist[t*256+j];
      if(run + c >= k){
        if(mode == 0){ state[0] = (unsigned)(t*256+j); state[1] = k - run; }
        else { state[2] = (state[0] << 16) | (unsigned)(t*256+j); state[3] = k - run; }
        break;
      }
      run += c;
    }
  }
}

// ---------- mask + gate + alive-list + fused per-block readout partials ----------
__global__ __launch_bounds__(256) void k_maskCR(unsigned* __restrict__ key,
        const float* __restrict__ score, const unsigned* __restrict__ state,
        const unsigned short* __restrict__ h16,
        unsigned char* __restrict__ selm, float* __restrict__ gate,
        int* __restrict__ alist_out, unsigned* __restrict__ acounter,
        float* __restrict__ rpart, int slotbase){
  __shared__ int wcnt[4];
  __shared__ int priorSh;
  __shared__ int redi[256];
  __shared__ float gl[256];
  __shared__ unsigned char slf[256];
  __shared__ float4 red[256];
  __shared__ float out2[256];
  int t = threadIdx.x;
  int i = blockIdx.x*256 + t;
  unsigned T = state[2];
  int trem = (int)state[3];
  unsigned kv = (i < NN) ? key[i] : 0u;
  bool match = (kv == T);
  unsigned long long m = __ballot(match);
  int lane = t & 63, wid = t >> 6;
  if(lane == 0) wcnt[wid] = __popcll(m);
  if(t == 0) priorSh = 0;
  __syncthreads();
  int hasMatch = wcnt[0] | wcnt[1] | wcnt[2] | wcnt[3];
  int bbase = blockIdx.x*256;
  if(hasMatch){   // rare: only blocks containing threshold-tied keys
    int cm = 0;
    for(int j = t*4; j < bbase; j += 1024){
      uint4 kk = *(const uint4*)&key[j];
      cm += (kk.x==T) + (kk.y==T) + (kk.z==T) + (kk.w==T);
    }
    redi[t] = cm;
    __syncthreads();
    for(int off=128; off>0; off>>=1){
      if(t < off) redi[t] += redi[t+off];
      __syncthreads();
    }
    if(t == 0) priorSh = redi[0];
    __syncthreads();
  }
  int pre = 0;
  for(int w=0; w<wid; w++) pre += wcnt[w];
  int lrank = __popcll(m & ((1ull << lane) - 1ull));
  int rank = priorSh + pre + lrank;
  bool sel = (kv > T) || (match && rank < trem);
  float gg = sel ? tanhf(score[i]) : 0.f;
  gl[t] = gg;
  slf[t] = sel ? 1 : 0;
  if(i < NN){
    selm[i] = sel ? 1 : 0;
    gate[i] = gg;
    if(!sel) key[i] = 0u;     // dead keys must be 0 for next layer's select
  }
  unsigned long long sm = __ballot(sel);
  unsigned abase = 0;
  if(lane == 0) abase = atomicAdd(acounter, (unsigned)__popcll(sm));
  abase = (unsigned)__shfl((int)abase, 0, 64);
  if(sel) alist_out[abase + __popcll(sm & ((1ull << lane) - 1ull))] = i;
  __syncthreads();
  // readout partials over this block's selected nodes: 16 col-lanes x 16 node-slots
  int ch = t & 15;
  int slot = t >> 4;
  float mm[8] = {0,0,0,0,0,0,0,0};
  float MM[8] = {-1e30f,-1e30f,-1e30f,-1e30f,-1e30f,-1e30f,-1e30f,-1e30f};
  for(int itr=0; itr<16; itr++){
    int nl = slot + itr*16;
    int node = bbase + nl;
    if(node < NN && slf[nl]){
      float g = gl[nl];
      uint4 v = ((const uint4*)(h16 + (size_t)node*HH))[ch];
      float x0 = g*bflo_(v.x), x1 = g*bfhi_(v.x);
      float x2 = g*bflo_(v.y), x3 = g*bfhi_(v.y);
      float x4 = g*bflo_(v.z), x5 = g*bfhi_(v.z);
      float x6 = g*bflo_(v.w), x7 = g*bfhi_(v.w);
      mm[0]+=x0; mm[1]+=x1; mm[2]+=x2; mm[3]+=x3;
      mm[4]+=x4; mm[5]+=x5; mm[6]+=x6; mm[7]+=x7;
      MM[0]=fmaxf(MM[0],x0); MM[1]=fmaxf(MM[1],x1); MM[2]=fmaxf(MM[2],x2); MM[3]=fmaxf(MM[3],x3);
      MM[4]=fmaxf(MM[4],x4); MM[5]=fmaxf(MM[5],x5); MM[6]=fmaxf(MM[6],x6); MM[7]=fmaxf(MM[7],x7);
    }
  }
  #pragma unroll
  for(int half=0; half<2; half++){
    red[t] = make_float4(mm[half*4+0],mm[half*4+1],mm[half*4+2],mm[half*4+3]);
    __syncthreads();
    if(t < 16){
      float4 sacc = red[t];
      for(int j=1;j<16;j++){
        float4 o = red[t + 16*j];
        sacc.x += o.x; sacc.y += o.y; sacc.z += o.z; sacc.w += o.w;
      }
      int d = t*8 + half*4;
      out2[d+0] = sacc.x; out2[d+1] = sacc.y; out2[d+2] = sacc.z; out2[d+3] = sacc.w;
    }
    __syncthreads();
    red[t] = make_float4(MM[half*4+0],MM[half*4+1],MM[half*4+2],MM[half*4+3]);
    __syncthreads();
    if(t < 16){
      float4 sacc = red[t];
      for(int j=1;j<16;j++){
        float4 o = red[t + 16*j];
        sacc.x = fmaxf(sacc.x,o.x); sacc.y = fmaxf(sacc.y,o.y);
        sacc.z = fmaxf(sacc.z,o.z); sacc.w = fmaxf(sacc.w,o.w);
      }
      int d = 128 + t*8 + half*4;
      out2[d+0] = sacc.x; out2[d+1] = sacc.y; out2[d+2] = sacc.z; out2[d+3] = sacc.w;
    }
    __syncthreads();
  }
  rpart[(size_t)(slotbase + blockIdx.x)*256 + t] = out2[t];
}

// ---------- parallel edge compaction: 16 lanes/node, 1 global atomic/block ----------
__global__ __launch_bounds__(256) void k_compact(const int* __restrict__ alist, int n,
        const unsigned char* __restrict__ selm,
        const int* __restrict__ rs_old, const int* __restrict__ rl_old,
        const int* __restrict__ col_old,
        int* __restrict__ rs_new, int* __restrict__ rl_new, int* __restrict__ col_new,
        float* __restrict__ dinv, unsigned* __restrict__ ecnt){
  __shared__ unsigned gcnt[16];
  __shared__ unsigned gbase[16];
  __shared__ unsigned blkbase;
  int t = threadIdx.x;
  int g = t >> 4, lane = t & 15;
  int gsh = ((t >> 4) & 3) * 16;   // group's bit offset within the 64-lane ballot
  int idx = blockIdx.x*16 + g;
  int node = -1, e0 = 0, len = 0;
  if(idx < n){ node = alist[idx]; e0 = rs_old[node]; len = rl_old[node]; }
  int cnt = 0;
  for(int i=lane; i<len; i+=16) cnt += selm[col_old[e0+i]];
  cnt += __shfl_xor(cnt,1,64); cnt += __shfl_xor(cnt,2,64);
  cnt += __shfl_xor(cnt,4,64); cnt += __shfl_xor(cnt,8,64);
  if(lane == 0) gcnt[g] = (node >= 0) ? (unsigned)cnt : 0u;
  __syncthreads();
  if(t == 0){
    unsigned s = 0;
    for(int j=0;j<16;j++){ gbase[j] = s; s += gcnt[j]; }
    blkbase = s ? atomicAdd(ecnt, s) : 0u;
  }
  __syncthreads();
  unsigned base = blkbase + gbase[g];
  if(node >= 0 && lane == 0){
    rs_new[node] = (int)base;
    rl_new[node] = cnt;
    dinv[node] = rsqrtf(1.f + (float)cnt);
  }
  int pos = (int)base;
  for(int i0=0; i0<len; i0+=16){
    int i = i0 + lane;
    bool keep = false; int s = 0;
    if(i < len){ s = col_old[e0+i]; keep = (selm[s] != 0); }
    unsigned long long b = __ballot(keep);
    unsigned gb = (unsigned)((b >> gsh) & 0xFFFFull);
    int rank = __popc(gb & ((1u << lane) - 1u));
    if(keep) col_new[pos + rank] = s;
    pos += __popc(gb);
  }
}

// ---------- final reduce of readout partials + MLP head + log_softmax ----------
__global__ void k_mlp(const float* __restrict__ rpart,
                      const float* __restrict__ M1, const float* __restrict__ bm1,
                      const float* __restrict__ M2, const float* __restrict__ bm2,
                      const float* __restrict__ M3, const float* __restrict__ bm3,
                      float* __restrict__ out){
  __shared__ float R[256];
  __shared__ float y1[128];
  __shared__ float y2[64];
  __shared__ float y3[16];
  int t = threadIdx.x;
  const float kinv[3] = {1.f/50000.f, 1.f/25000.f, 1.f/12500.f};
  if(t < 128){
    float acc = 0.f;
    for(int l=0; l<3; l++){
      float s0=0.f,s1=0.f,s2=0.f,s3=0.f;
      int base = l*NB_N;
      int j = 0;
      for(; j+3 < NB_N; j += 4){
        s0 += rpart[(size_t)(base+j  )*256 + t];
        s1 += rpart[(size_t)(base+j+1)*256 + t];
        s2 += rpart[(size_t)(base+j+2)*256 + t];
        s3 += rpart[(size_t)(base+j+3)*256 + t];
      }
      for(; j < NB_N; j++) s0 += rpart[(size_t)(base+j)*256 + t];
      acc += ((s0+s1)+(s2+s3)) * kinv[l];
    }
    R[t] = acc;
  } else {
    float acc = 0.f;
    for(int l=0; l<3; l++){
      float m0=-1e30f,m1=-1e30f,m2=-1e30f,m3=-1e30f;
      int base = l*NB_N;
      int j = 0;
      for(; j+3 < NB_N; j += 4){
        m0 = fmaxf(m0, rpart[(size_t)(base+j  )*256 + t]);
        m1 = fmaxf(m1, rpart[(size_t)(base+j+1)*256 + t]);
        m2 = fmaxf(m2, rpart[(size_t)(base+j+2)*256 + t]);
        m3 = fmaxf(m3, rpart[(size_t)(base+j+3)*256 + t]);
      }
      for(; j < NB_N; j++) m0 = fmaxf(m0, rpart[(size_t)(base+j)*256 + t]);
      acc += fmaxf(fmaxf(m0,m1), fmaxf(m2,m3));
    }
    R[t] = acc;
  }
  __syncthreads();
  if(t < 128){
    float a = bm1[t];
    for(int d=0; d<256; d++) a += R[d]*M1[d*128+t];
    y1[t] = fmaxf(a, 0.f);
  }
  __syncthreads();
  if(t < 64){
    float a = bm2[t];
    for(int d=0; d<128; d++) a += y1[d]*M2[d*64+t];
    y2[t] = fmaxf(a, 0.f);
  }
  __syncthreads();
  if(t < 10){
    float a = bm3[t];
    for(int d=0; d<64; d++) a += y2[d]*M3[d*10+t];
    y3[t] = a;
  }
  __syncthreads();
  if(t == 0){
    float mx = -1e30f;
    for(int o=0;o<10;o++) mx = fmaxf(mx, y3[o]);
    float s = 0.f;
    for(int o=0;o<10;o++) s += expf(y3[o]-mx);
    float ls = logf(s);
    for(int o=0;o<10;o++) out[o] = y3[o] - mx - ls;
  }
}

extern "C" void kernel_launch(void* const* d_in, const int* in_sizes, int n_in,
                              void* d_out, int out_size, void* d_ws, size_t ws_size,
                              hipStream_t stream){
  (void)in_sizes; (void)n_in; (void)out_size; (void)ws_size;
  const float* x  = (const float*)d_in[0];
  const int*   ei = (const int*)d_in[1];
  const float* W[3]   = {(const float*)d_in[2],  (const float*)d_in[6],  (const float*)d_in[10]};
  const float* bb[3]  = {(const float*)d_in[3],  (const float*)d_in[7],  (const float*)d_in[11]};
  const float* wsc[3] = {(const float*)d_in[4],  (const float*)d_in[8],  (const float*)d_in[12]};
  const float* bsc[3] = {(const float*)d_in[5],  (const float*)d_in[9],  (const float*)d_in[13]};
  const float* M1  = (const float*)d_in[14];
  const float* bm1 = (const float*)d_in[15];
  const float* M2  = (const float*)d_in[16];
  const float* bm2 = (const float*)d_in[17];
  const float* M3  = (const float*)d_in[18];
  const float* bm3 = (const float*)d_in[19];
  float* out = (float*)d_out;

  char* base = (char*)d_ws;
  size_t off = 0;
  auto alloc = [&](size_t bytes)->char*{
    char* ptr = base + off;
    off += (bytes + 511) & ~(size_t)511;
    return ptr;
  };
  unsigned short* y16  = (unsigned short*)alloc((size_t)NN*HH*2);
  unsigned short* h16  = (unsigned short*)alloc((size_t)NN*HH*2);
  int*      col0      = (int*)     alloc((size_t)EE*4);
  int*      col1      = (int*)     alloc((size_t)EE*4);
  int*      col2      = (int*)     alloc((size_t)EE*4);
  unsigned* staging   = (unsigned*)alloc((size_t)NBKT*CAP*4);
  int*      rs0       = (int*)     alloc((size_t)NN*4);
  int*      rl0       = (int*)     alloc((size_t)NN*4);
  int*      rs1       = (int*)     alloc((size_t)NN*4);
  int*      rl1       = (int*)     alloc((size_t)NN*4);
  int*      rs2       = (int*)     alloc((size_t)NN*4);
  int*      rl2       = (int*)     alloc((size_t)NN*4);
  float*    dinv      = (float*)   alloc((size_t)NN*4);
  float*    pbuf      = (float*)   alloc((size_t)NN*4);
  float*    score     = (float*)   alloc((size_t)NN*4);
  float*    gate      = (float*)   alloc((size_t)NN*4);
  unsigned* key       = (unsigned*)alloc((size_t)NN*4);
  unsigned char* selm = (unsigned char*)alloc((size_t)NN);
  int*      alistA    = (int*)     alloc((size_t)50000*4);
  int*      alistB    = (int*)     alloc((size_t)25000*4);
  unsigned* hist      = (unsigned*)alloc((size_t)2*65536*4);
  unsigned* bktcnt    = (unsigned*)alloc((size_t)(NBKT+1)*4);
  unsigned* state     = (unsigned*)alloc(256);
  float*    rpart     = (float*)   alloc((size_t)3*NB_N*256*4);

  // CSR build
  k_edgeflag<<<1,256,0,stream>>>(ei, state, bktcnt);
  k_binA<<<NBKT,256,0,stream>>>(ei, state, bktcnt, staging);
  k_binB<<<NBKT,256,0,stream>>>(staging, bktcnt, rs0, rl0, col0, dinv);

  // ---- layer 1 (identity rows: all 100000 alive) ----
  k_gemm<0><<<dim3(1563,2),256,0,stream>>>(x, nullptr, nullptr, NN, W[0], y16);
  k_agg<0><<<25000,256,0,stream>>>(y16, dinv, rs0, rl0, col0, nullptr, bb[0], wsc[0], h16, pbuf, hist);
  k_score<0><<<NB_N,256,0,stream>>>(pbuf, dinv, rs0, rl0, col0, nullptr, NN, bsc[0], score, key, hist);
  k_pick<<<1,256,0,stream>>>(hist, state, 50000, 0);
  k_hist_lo<<<NB_N,256,0,stream>>>(key, state, hist + 65536);
  k_pick<<<1,256,0,stream>>>(hist + 65536, state, 0, 1);
  k_maskCR<<<NB_N,256,0,stream>>>(key, score, state, h16, selm, gate, alistA, state+12, rpart, 0);
  k_compact<<<3125,256,0,stream>>>(alistA, 50000, selm, rs0, rl0, col0, rs1, rl1, col1, dinv, state+16);

  // ---- layer 2 (50000 alive) ----
  k_gemm<1><<<dim3(782,2),256,0,stream>>>(h16, gate, alistA, 50000, W[1], y16);
  k_agg<1><<<12500,256,0,stream>>>(y16, dinv, rs1, rl1, col1, alistA, bb[1], wsc[1], h16, pbuf, hist);
  k_score<1><<<196,256,0,stream>>>(pbuf, dinv, rs1, rl1, col1, alistA, 50000, bsc[1], score, key, hist);
  k_pick<<<1,256,0,stream>>>(hist, state, 25000, 0);
  k_hist_lo<<<NB_N,256,0,stream>>>(key, state, hist + 65536);
  k_pick<<<1,256,0,stream>>>(hist + 65536, state, 0, 1);
  k_maskCR<<<NB_N,256,0,stream>>>(key, score, state, h16, selm, gate, alistB, state+13, rpart, NB_N);
  k_compact<<<1563,256,0,stream>>>(alistB, 25000, selm, rs1, rl1, col1, rs2, rl2, col2, dinv, state+17);

  // ---- layer 3 (25000 alive) ----
  k_gemm<1><<<dim3(391,2),256,0,stream>>>(h16, gate, alistB, 25000, W[2], y16);
  k_agg<1><<<6250,256,0,stream>>>(y16, dinv, rs2, rl2, col2, alistB, bb[2], wsc[2], h16, pbuf, hist);
  k_score<1><<<98,256,0,stream>>>(pbuf, dinv, rs2, rl2, col2, alistB, 25000, bsc[2], score, key, hist);
  k_pick<<<1,256,0,stream>>>(hist, state, 12500, 0);
  k_hist_lo<<<NB_N,256,0,stream>>>(key, state, hist + 65536);
  k_pick<<<1,256,0,stream>>>(hist + 65536, state, 0, 1);
  k_maskCR<<<NB_N,256,0,stream>>>(key, score, state, h16, selm, gate, alistA, state+14, rpart, 2*NB_N);

  k_mlp<<<1,256,0,stream>>>(rpart, M1, bm1, M2, bm2, M3, bm3, out);
}